// Round 15
// baseline (309.600 us; speedup 1.0000x reference)
//
#include <hip/hip_runtime.h>
#include <math.h>

#define D_MODEL 1024
#define SEQ     2048
#define NB      2
#define NH      16
#define DH      64
#define ROWS    (NB*SEQ)                  // 4096
#define OUT_ELEMS ((size_t)ROWS*D_MODEL)  // 4194304

typedef short bf16x8 __attribute__((ext_vector_type(8)));
typedef short bf16x4 __attribute__((ext_vector_type(4)));
typedef float f32x4  __attribute__((ext_vector_type(4)));

#define AS1 __attribute__((address_space(1)))
#define AS3 __attribute__((address_space(3)))

__device__ __forceinline__ float bf2f(short u){
    union{float f; unsigned v;} x; x.v = ((unsigned)(unsigned short)u) << 16; return x.f;
}
__device__ __forceinline__ short f2bf(float f){
    union{float f; unsigned v;} x; x.f = f;
    unsigned r = (x.v + 0x7FFF + ((x.v >> 16) & 1)) >> 16;   // RNE
    return (short)r;
}
__device__ __forceinline__ int swz8(int row, int slot){ return slot ^ ((row + (row>>3)) & 7); }

#define MFMA16(a,b,c) __builtin_amdgcn_mfma_f32_16x16x32_bf16((a),(b),(c),0,0,0)

// exp(x*0.125) = exp2(x * 0.125*log2(e))
#define EXPSC 0.18033688011112042f

// ---------------------------------------------------------------------------
// Prep: weights fp32->bf16, x inputs fp32->bf16 (into attn-slice scratch),
// RoPE cos/sin table.  Grid: 16640 blocks.
// ---------------------------------------------------------------------------
__global__ __launch_bounds__(256) void prep(const float* __restrict__ Wq,
                                            const float* __restrict__ Wk,
                                            const float* __restrict__ Wv,
                                            const float* __restrict__ Wo,
                                            const float* __restrict__ qx,
                                            const float* __restrict__ kx,
                                            const float* __restrict__ vx,
                                            short* __restrict__ wqkv,
                                            short* __restrict__ wob,
                                            short* __restrict__ xb,
                                            float* __restrict__ tab)
{
    int i = blockIdx.x*256 + threadIdx.x;
    if (i < 1048576) {                           // 4 weights, 262144 float4 each
        int sel = i >> 18;
        int loc = i & 262143;
        const float* src = sel==0 ? Wq : sel==1 ? Wk : sel==2 ? Wv : Wo;
        short* dst = sel < 3 ? wqkv + (size_t)sel*1048576 : wob;
        float4 v = *(const float4*)&src[(size_t)loc*4];
        bf16x4 o = { f2bf(v.x), f2bf(v.y), f2bf(v.z), f2bf(v.w) };
        *(bf16x4*)&dst[(size_t)loc*4] = o;
    } else if (i < 4194304) {                    // 3 x-inputs, 1048576 float4 each
        int e = i - 1048576;
        int sel = e >> 20;
        int loc = e & 1048575;
        const float* src = sel==0 ? qx : sel==1 ? kx : vx;
        short* dst = xb + (size_t)sel*OUT_ELEMS;
        float4 v = *(const float4*)&src[(size_t)loc*4];
        bf16x4 o = { f2bf(v.x), f2bf(v.y), f2bf(v.z), f2bf(v.w) };
        *(bf16x4*)&dst[(size_t)loc*4] = o;
    } else {                                     // 65536 table entries
        int e = i - 4194304;
        int j = e & 31, s = e >> 5;
        float ang = (float)s * exp2f(-(float)j * 0.41524101186092437f);
        float sn, cs; sincosf(ang, &sn, &cs);    // accurate large-arg reduction
        tab[(size_t)s*64 + j*2]     = cs;
        tab[(size_t)s*64 + j*2 + 1] = sn;
    }
}

// ---------------------------------------------------------------------------
// Fused QKV projection, pure bf16, BK=64, source-pre-swizzled staging
// (conflict-free fragment reads).  z=0: Q (rope fused) -> qb.
// z=1: K (rope fused) -> kb.  z=2: V -> vbt TRANSPOSED [bh][d][s].
// ---------------------------------------------------------------------------
__global__ __launch_bounds__(256) void gemm_qkv(const short* __restrict__ xb,
                                                const short* __restrict__ wqkv,
                                                const float* __restrict__ tab,
                                                short* __restrict__ qb,
                                                short* __restrict__ kb,
                                                short* __restrict__ vbt)
{
    const int z = blockIdx.z;
    const short* A = xb + (size_t)z*OUT_ELEMS;
    const short* B = wqkv + (size_t)z*D_MODEL*D_MODEL;

    __shared__ __align__(16) short Alds[128*64];   // 16 KB, rows of 64 bf16
    __shared__ __align__(16) short Blds[128*64];
    const int t = threadIdx.x, lane = t & 63, wid = t >> 6;
    const int m0 = blockIdx.y << 7, n0 = blockIdx.x << 7;
    const int wm = (wid >> 1) << 6, wn = (wid & 1) << 6;
    const int l15 = lane & 15, l4 = lane >> 4;
    const int gchunk = (lane & 7) ^ (lane >> 3);   // pre-swizzled k-chunk
    const int rxor = l15 & 7;                      // read-side XOR (row&7)

    f32x4 acc[4][4] = {};

    for (int k0 = 0; k0 < D_MODEL; k0 += 64) {
        __syncthreads();
        #pragma unroll
        for (int u = 0; u < 4; ++u) {
            int row = u*32 + wid*8 + (lane >> 3);  // = (u*256+t)>>3
            const short* ga = &A[(size_t)(m0 + row)*D_MODEL + k0 + gchunk*8];
            const short* gb = &B[(size_t)(n0 + row)*D_MODEL + k0 + gchunk*8];
            __builtin_amdgcn_global_load_lds((const AS1 unsigned*)ga,
                (AS3 unsigned*)&Alds[u*2048 + wid*512], 16, 0, 0);
            __builtin_amdgcn_global_load_lds((const AS1 unsigned*)gb,
                (AS3 unsigned*)&Blds[u*2048 + wid*512], 16, 0, 0);
        }
        __syncthreads();
        #pragma unroll
        for (int kk = 0; kk < 2; ++kk) {
            bf16x8 af[4], bfr[4];
            #pragma unroll
            for (int mf = 0; mf < 4; ++mf)
                af[mf] = *(const bf16x8*)&Alds[(wm + mf*16 + l15)*64
                                               + ((kk*4 + l4) ^ rxor)*8];
            #pragma unroll
            for (int nf = 0; nf < 4; ++nf)
                bfr[nf] = *(const bf16x8*)&Blds[(wn + nf*16 + l15)*64
                                                + ((kk*4 + l4) ^ rxor)*8];
            #pragma unroll
            for (int mf = 0; mf < 4; ++mf)
                #pragma unroll
                for (int nf = 0; nf < 4; ++nf)
                    acc[mf][nf] = MFMA16(af[mf], bfr[nf], acc[mf][nf]);
        }
    }

    // C/D layout: col = lane&15, row = (lane>>4)*4 + j
    if (z < 2) {
        short* C = z==0 ? qb : kb;
        #pragma unroll
        for (int mf = 0; mf < 4; ++mf)
            #pragma unroll
            for (int j = 0; j < 4; ++j) {
                int row = m0 + wm + mf*16 + l4*4 + j;
                int s = row & (SEQ-1);
                #pragma unroll
                for (int p = 0; p < 2; ++p) {          // (d, d+32) pairs
                    int d31 = p*16 + l15;              // rotation index 0..31
                    float2 cs2 = *(const float2*)&tab[(size_t)s*64 + d31*2];
                    float x1 = acc[mf][p][j], x2 = acc[mf][p+2][j];
                    size_t rb = (size_t)row*D_MODEL + n0 + wn;
                    C[rb + p*16 + l15]       = f2bf(x1*cs2.x - x2*cs2.y);
                    C[rb + (p+2)*16 + l15]   = f2bf(x1*cs2.y + x2*cs2.x);
                }
            }
    } else {
        #pragma unroll
        for (int nf = 0; nf < 4; ++nf) {
            int col = n0 + wn + nf*16 + l15;
            int hh = col >> 6, d = col & 63;
            #pragma unroll
            for (int mf = 0; mf < 4; ++mf)
                #pragma unroll
                for (int j = 0; j < 4; ++j) {
                    int row = m0 + wm + mf*16 + l4*4 + j;
                    int b = row >> 11, s = row & (SEQ-1);
                    vbt[(((size_t)(b*NH + hh))*DH + d)*SEQ + s] = f2bf(acc[mf][nf][j]);
                }
        }
    }
}

// ---------------------------------------------------------------------------
// Output projection, same BK=64 swizzled structure: out = aob@wob^T + bo.
// ---------------------------------------------------------------------------
__global__ __launch_bounds__(256) void gemm_out(const short* __restrict__ A,
                                                const short* __restrict__ B,
                                                const float* __restrict__ bias,
                                                float* __restrict__ Cout)
{
    __shared__ __align__(16) short Alds[128*64];
    __shared__ __align__(16) short Blds[128*64];
    const int t = threadIdx.x, lane = t & 63, wid = t >> 6;
    const int m0 = blockIdx.y << 7, n0 = blockIdx.x << 7;
    const int wm = (wid >> 1) << 6, wn = (wid & 1) << 6;
    const int l15 = lane & 15, l4 = lane >> 4;
    const int gchunk = (lane & 7) ^ (lane >> 3);
    const int rxor = l15 & 7;

    f32x4 acc[4][4] = {};

    for (int k0 = 0; k0 < D_MODEL; k0 += 64) {
        __syncthreads();
        #pragma unroll
        for (int u = 0; u < 4; ++u) {
            int row = u*32 + wid*8 + (lane >> 3);
            const short* ga = &A[(size_t)(m0 + row)*D_MODEL + k0 + gchunk*8];
            const short* gb = &B[(size_t)(n0 + row)*D_MODEL + k0 + gchunk*8];
            __builtin_amdgcn_global_load_lds((const AS1 unsigned*)ga,
                (AS3 unsigned*)&Alds[u*2048 + wid*512], 16, 0, 0);
            __builtin_amdgcn_global_load_lds((const AS1 unsigned*)gb,
                (AS3 unsigned*)&Blds[u*2048 + wid*512], 16, 0, 0);
        }
        __syncthreads();
        #pragma unroll
        for (int kk = 0; kk < 2; ++kk) {
            bf16x8 af[4], bfr[4];
            #pragma unroll
            for (int mf = 0; mf < 4; ++mf)
                af[mf] = *(const bf16x8*)&Alds[(wm + mf*16 + l15)*64
                                               + ((kk*4 + l4) ^ rxor)*8];
            #pragma unroll
            for (int nf = 0; nf < 4; ++nf)
                bfr[nf] = *(const bf16x8*)&Blds[(wn + nf*16 + l15)*64
                                                + ((kk*4 + l4) ^ rxor)*8];
            #pragma unroll
            for (int mf = 0; mf < 4; ++mf)
                #pragma unroll
                for (int nf = 0; nf < 4; ++nf)
                    acc[mf][nf] = MFMA16(af[mf], bfr[nf], acc[mf][nf]);
        }
    }

    #pragma unroll
    for (int nf = 0; nf < 4; ++nf) {
        int col = n0 + wn + nf*16 + l15;
        float bv = bias[col];
        #pragma unroll
        for (int mf = 0; mf < 4; ++mf)
            #pragma unroll
            for (int j = 0; j < 4; ++j) {
                int row = m0 + wm + mf*16 + l4*4 + j;
                Cout[(size_t)row*D_MODEL + col] = acc[mf][nf][j] + bv;
            }
    }
}

// ---------------------------------------------------------------------------
// Fused two-loop flash attention — 4 waves x 32 q-rows (two 16-row subtiles
// per wave): each staged K/V fragment is read ONCE and feeds 2 MFMAs, so
// per-q-row LDS fragment traffic and barrier count HALVE vs 8-wave/16-q.
// Otherwise r10 structure: dbuf staging, swapped QK^T -> P[k][q] (q=lane&15),
// fixed-max softmax, NT f32x4 weight stores, b64 P-pack wave-private.
// Block = (b,h,128 q-rows), 256 thr, LDS 48 KB -> 3 blocks/CU.
// ---------------------------------------------------------------------------
__global__ __launch_bounds__(256) void attn_fused(const short* __restrict__ qb,
                                                  const short* __restrict__ kb,
                                                  const short* __restrict__ vbt,
                                                  float* __restrict__ attn,
                                                  short* __restrict__ aob)
{
    __shared__ __align__(16) short Klds[2][64*64];
    __shared__ __align__(16) short Vt  [2][64*64];
    __shared__ __align__(16) short Plds[4*2*16*64];   // per wave, 2 subtiles
    const int t = threadIdx.x, lane = t & 63, wv = t >> 6;   // wv 0..3
    const int bid = blockIdx.x;
    const int nb = (bid & 7)*64 + (bid >> 3);       // XCD swizzle (512 = 8*64)
    const int rb = nb & 15, bh = nb >> 4;           // bh = b*16+h
    const int h = bh & 15;
    const size_t bs0 = (size_t)(bh >> 4) * SEQ;
    const int qrow0 = rb << 7;
    const int l15 = lane & 15, l4 = lane >> 4;
    // staging: 512 slots, 2 per thread (rows sr0, sr0+32)
    const int sr0 = t >> 3, ssl = t & 7;
    const int soff0 = sr0*64 + swz8(sr0, ssl)*8;
    const int soff1 = (sr0+32)*64 + swz8(sr0+32, ssl)*8;

    // Q fragments for both 16-row subtiles (B-operand: lane&15 = q-column)
    bf16x8 qf[2][2];
    #pragma unroll
    for (int sub = 0; sub < 2; ++sub) {
        int qrow = qrow0 + wv*32 + sub*16 + l15;
        const short* qp = &qb[(bs0 + qrow)*D_MODEL + h*DH + l4*8];
        qf[sub][0] = *(const bf16x8*)&qp[0];
        qf[sub][1] = *(const bf16x8*)&qp[32];
    }

    const short* kbase0  = &kb[(bs0 + sr0)*D_MODEL + h*DH + ssl*8];
    const short* kbase1  = &kb[(bs0 + sr0 + 32)*D_MODEL + h*DH + ssl*8];
    const short* vtbase0 = &vbt[((size_t)bh*DH + sr0)*SEQ + ssl*8];
    const short* vtbase1 = &vbt[((size_t)bh*DH + sr0 + 32)*SEQ + ssl*8];

    // ---- loop 1: denominators (fixed max = 0, lane-local partial sums) --
    float lsum0 = 0.f, lsum1 = 0.f;
    {
        bf16x8 kr0 = *(const bf16x8*)&kbase0[0];
        bf16x8 kr1 = *(const bf16x8*)&kbase1[0];
        *(bf16x8*)&Klds[0][soff0] = kr0;
        *(bf16x8*)&Klds[0][soff1] = kr1;
        kr0 = *(const bf16x8*)&kbase0[(size_t)64*D_MODEL];
        kr1 = *(const bf16x8*)&kbase1[(size_t)64*D_MODEL];
        __syncthreads();
        int cur = 0;
        for (int kt = 0; kt < SEQ; kt += 64, cur ^= 1) {
            if (kt + 64 < SEQ) {
                *(bf16x8*)&Klds[cur^1][soff0] = kr0;
                *(bf16x8*)&Klds[cur^1][soff1] = kr1;
                if (kt + 128 < SEQ) {
                    kr0 = *(const bf16x8*)&kbase0[(size_t)(kt+128)*D_MODEL];
                    kr1 = *(const bf16x8*)&kbase1[(size_t)(kt+128)*D_MODEL];
                }
            }
            f32x4 sc0[4] = {}, sc1[4] = {};
            __builtin_amdgcn_s_setprio(1);
            #pragma unroll
            for (int kk = 0; kk < 2; ++kk)
                #pragma unroll
                for (int nf = 0; nf < 4; ++nf) {
                    int krow = nf*16 + l15;
                    bf16x8 kf = *(const bf16x8*)&Klds[cur][krow*64 + swz8(krow, kk*4 + l4)*8];
                    sc0[nf] = MFMA16(kf, qf[0][kk], sc0[nf]);  // swapped: D[k][q]
                    sc1[nf] = MFMA16(kf, qf[1][kk], sc1[nf]);
                }
            __builtin_amdgcn_s_setprio(0);
            #pragma unroll
            for (int nf = 0; nf < 4; ++nf)
                #pragma unroll
                for (int j = 0; j < 4; ++j) {
                    lsum0 += exp2f(sc0[nf][j]*EXPSC);
                    lsum1 += exp2f(sc1[nf][j]*EXPSC);
                }
            __syncthreads();
        }
    }
    lsum0 += __shfl_xor(lsum0, 16);
    lsum0 += __shfl_xor(lsum0, 32);
    lsum1 += __shfl_xor(lsum1, 16);
    lsum1 += __shfl_xor(lsum1, 32);
    const float li0 = 1.0f / lsum0;
    const float li1 = 1.0f / lsum1;

    // ---- loop 2: weights + PV -------------------------------------------
    f32x4 o0[4] = {}, o1[4] = {};
    const size_t wrow0 = ((size_t)bh*SEQ + qrow0 + wv*32 + l15)*SEQ;
    const size_t wrow1 = wrow0 + (size_t)16*SEQ;
    short* pb0 = &Plds[(wv*2 + 0)*1024 + l15*64];
    short* pb1 = &Plds[(wv*2 + 1)*1024 + l15*64];
    {
        bf16x8 kr0 = *(const bf16x8*)&kbase0[0];
        bf16x8 kr1 = *(const bf16x8*)&kbase1[0];
        bf16x8 vr0 = *(const bf16x8*)&vtbase0[0];
        bf16x8 vr1 = *(const bf16x8*)&vtbase1[0];
        *(bf16x8*)&Klds[0][soff0] = kr0;
        *(bf16x8*)&Klds[0][soff1] = kr1;
        *(bf16x8*)&Vt  [0][soff0] = vr0;
        *(bf16x8*)&Vt  [0][soff1] = vr1;
        kr0 = *(const bf16x8*)&kbase0[(size_t)64*D_MODEL];
        kr1 = *(const bf16x8*)&kbase1[(size_t)64*D_MODEL];
        vr0 = *(const bf16x8*)&vtbase0[64];
        vr1 = *(const bf16x8*)&vtbase1[64];
        __syncthreads();
        int cur = 0;
        for (int kt = 0; kt < SEQ; kt += 64, cur ^= 1) {
            if (kt + 64 < SEQ) {
                *(bf16x8*)&Klds[cur^1][soff0] = kr0;
                *(bf16x8*)&Klds[cur^1][soff1] = kr1;
                *(bf16x8*)&Vt  [cur^1][soff0] = vr0;
                *(bf16x8*)&Vt  [cur^1][soff1] = vr1;
                if (kt + 128 < SEQ) {
                    kr0 = *(const bf16x8*)&kbase0[(size_t)(kt+128)*D_MODEL];
                    kr1 = *(const bf16x8*)&kbase1[(size_t)(kt+128)*D_MODEL];
                    vr0 = *(const bf16x8*)&vtbase0[kt+128];
                    vr1 = *(const bf16x8*)&vtbase1[kt+128];
                }
            }
            f32x4 sc0[4] = {}, sc1[4] = {};
            __builtin_amdgcn_s_setprio(1);
            #pragma unroll
            for (int kk = 0; kk < 2; ++kk)
                #pragma unroll
                for (int nf = 0; nf < 4; ++nf) {
                    int krow = nf*16 + l15;
                    bf16x8 kf = *(const bf16x8*)&Klds[cur][krow*64 + swz8(krow, kk*4 + l4)*8];
                    sc0[nf] = MFMA16(kf, qf[0][kk], sc0[nf]);
                    sc1[nf] = MFMA16(kf, qf[1][kk], sc1[nf]);
                }
            __builtin_amdgcn_s_setprio(0);
            // lane holds P[k = nf*16 + l4*4 + j][q = l15] for each subtile
            #pragma unroll
            for (int nf = 0; nf < 4; ++nf) {
                float w0 = exp2f(sc0[nf][0]*EXPSC) * li0;
                float w1 = exp2f(sc0[nf][1]*EXPSC) * li0;
                float w2 = exp2f(sc0[nf][2]*EXPSC) * li0;
                float w3 = exp2f(sc0[nf][3]*EXPSC) * li0;
                f32x4 wv4 = { w0, w1, w2, w3 };
                __builtin_nontemporal_store(wv4,
                    (f32x4*)&attn[wrow0 + kt + nf*16 + l4*4]);
                bf16x4 pw = { f2bf(w0), f2bf(w1), f2bf(w2), f2bf(w3) };
                *(bf16x4*)&pb0[swz8(l15, nf*2 + (l4>>1))*8 + (l4&1)*4] = pw;
            }
            #pragma unroll
            for (int nf = 0; nf < 4; ++nf) {
                float w0 = exp2f(sc1[nf][0]*EXPSC) * li1;
                float w1 = exp2f(sc1[nf][1]*EXPSC) * li1;
                float w2 = exp2f(sc1[nf][2]*EXPSC) * li1;
                float w3 = exp2f(sc1[nf][3]*EXPSC) * li1;
                f32x4 wv4 = { w0, w1, w2, w3 };
                __builtin_nontemporal_store(wv4,
                    (f32x4*)&attn[wrow1 + kt + nf*16 + l4*4]);
                bf16x4 pw = { f2bf(w0), f2bf(w1), f2bf(w2), f2bf(w3) };
                *(bf16x4*)&pb1[swz8(l15, nf*2 + (l4>>1))*8 + (l4&1)*4] = pw;
            }
            // PV: vf read ONCE per (kk,nf), feeds both subtiles
            __builtin_amdgcn_s_setprio(1);
            #pragma unroll
            for (int kk = 0; kk < 2; ++kk) {
                bf16x8 pa0 = *(const bf16x8*)&pb0[swz8(l15, kk*4 + l4)*8];
                bf16x8 pa1 = *(const bf16x8*)&pb1[swz8(l15, kk*4 + l4)*8];
                #pragma unroll
                for (int nf = 0; nf < 4; ++nf) {
                    int d = nf*16 + l15;
                    bf16x8 vf = *(const bf16x8*)&Vt[cur][d*64 + swz8(d, kk*4 + l4)*8];
                    o0[nf] = MFMA16(pa0, vf, o0[nf]);
                    o1[nf] = MFMA16(pa1, vf, o1[nf]);
                }
            }
            __builtin_amdgcn_s_setprio(0);
            __syncthreads();
        }
    }
    #pragma unroll
    for (int nf = 0; nf < 4; ++nf)
        #pragma unroll
        for (int j = 0; j < 4; ++j) {
            int qr0 = qrow0 + wv*32 + l4*4 + j;
            aob[(bs0 + qr0)*D_MODEL + h*DH + nf*16 + l15]      = f2bf(o0[nf][j]);
            aob[(bs0 + qr0 + 16)*D_MODEL + h*DH + nf*16 + l15] = f2bf(o1[nf][j]);
        }
}

// ---------------------------------------------------------------------------
extern "C" void kernel_launch(void* const* d_in, const int* in_sizes, int n_in,
                              void* d_out, int out_size, void* d_ws, size_t ws_size,
                              hipStream_t stream)
{
    const float* query = (const float*)d_in[0];
    const float* key_  = (const float*)d_in[1];
    const float* value = (const float*)d_in[2];
    const float* Wq    = (const float*)d_in[3];
    const float* Wk    = (const float*)d_in[4];
    const float* Wv    = (const float*)d_in[5];
    const float* Wo    = (const float*)d_in[6];
    const float* bo    = (const float*)d_in[7];

    float* out  = (float*)d_out;
    float* attn = out + OUT_ELEMS;
    short* xb   = (short*)attn;                  // 24 MB scratch inside attn
                                                 // slice; overwritten by
                                                 // attn_fused later (safe:
                                                 // stream-ordered)

    // ws (shorts): wqkv 3M | wob 1M | qb 4M | kb 4M | vbt 4M | aob 4M | tab
    short* wqkv = (short*)d_ws;
    short* wob  = wqkv + (size_t)3*1048576;
    short* qb   = wob  + (size_t)1048576;
    short* kb   = qb + OUT_ELEMS;
    short* vbt  = kb + OUT_ELEMS;                // [bh=32][d=64][s=2048]
    short* aob  = vbt + OUT_ELEMS;
    float* tab  = (float*)(aob + OUT_ELEMS);     // 2048*64 floats (512 KB)

    dim3 blk(256);

    hipLaunchKernelGGL(prep, dim3(16640), blk, 0, stream,
                       Wq, Wk, Wv, Wo, query, key_, value, wqkv, wob, xb, tab);
    hipLaunchKernelGGL(gemm_qkv, dim3(8, 32, 3), blk, 0, stream,
                       xb, wqkv, tab, qb, kb, vbt);
    hipLaunchKernelGGL(attn_fused, dim3(512), blk, 0, stream,
                       qb, kb, vbt, attn, aob);
    hipLaunchKernelGGL(gemm_out, dim3(8, 32), blk, 0, stream, aob, wob, bo, out);
}

// Round 16
// 290.797 us; speedup vs baseline: 1.0647x; 1.0647x over previous
//
#include <hip/hip_runtime.h>
#include <hip/hip_bf16.h>
#include <math.h>

#define D_MODEL 1024
#define SEQ     2048
#define NB      2
#define NH      16
#define DH      64
#define ROWS    (NB*SEQ)                  // 4096
#define OUT_ELEMS ((size_t)ROWS*D_MODEL)  // 4194304

typedef short bf16x8 __attribute__((ext_vector_type(8)));
typedef short bf16x4 __attribute__((ext_vector_type(4)));
typedef float f32x4  __attribute__((ext_vector_type(4)));

#define AS1 __attribute__((address_space(1)))
#define AS3 __attribute__((address_space(3)))

__device__ __forceinline__ float bf2f(short u){
    union{float f; unsigned v;} x; x.v = ((unsigned)(unsigned short)u) << 16; return x.f;
}
// Compiler-friendly RNE conversion: hipcc pairs adjacent casts into
// v_cvt_pk_bf16_f32 (2 values/instr, HW RNE) — m240: scalar cast beats
// hand-rolled bit-twiddle AND inline-asm cvt_pk.
__device__ __forceinline__ short f2bf(float f){
    union { __hip_bfloat16 h; short s; } u;
    u.h = __float2bfloat16(f);
    return u.s;
}
__device__ __forceinline__ int swz8(int row, int slot){ return slot ^ ((row + (row>>3)) & 7); }

#define MFMA16(a,b,c) __builtin_amdgcn_mfma_f32_16x16x32_bf16((a),(b),(c),0,0,0)

// exp(x*0.125) = exp2(x * 0.125*log2(e))
#define EXPSC 0.18033688011112042f

// ---------------------------------------------------------------------------
// Prep: weights fp32->bf16, x inputs fp32->bf16 (into attn-slice scratch),
// RoPE cos/sin table.  Grid: 16640 blocks.
// ---------------------------------------------------------------------------
__global__ __launch_bounds__(256) void prep(const float* __restrict__ Wq,
                                            const float* __restrict__ Wk,
                                            const float* __restrict__ Wv,
                                            const float* __restrict__ Wo,
                                            const float* __restrict__ qx,
                                            const float* __restrict__ kx,
                                            const float* __restrict__ vx,
                                            short* __restrict__ wqkv,
                                            short* __restrict__ wob,
                                            short* __restrict__ xb,
                                            float* __restrict__ tab)
{
    int i = blockIdx.x*256 + threadIdx.x;
    if (i < 1048576) {                           // 4 weights, 262144 float4 each
        int sel = i >> 18;
        int loc = i & 262143;
        const float* src = sel==0 ? Wq : sel==1 ? Wk : sel==2 ? Wv : Wo;
        short* dst = sel < 3 ? wqkv + (size_t)sel*1048576 : wob;
        float4 v = *(const float4*)&src[(size_t)loc*4];
        bf16x4 o = { f2bf(v.x), f2bf(v.y), f2bf(v.z), f2bf(v.w) };
        *(bf16x4*)&dst[(size_t)loc*4] = o;
    } else if (i < 4194304) {                    // 3 x-inputs, 1048576 float4 each
        int e = i - 1048576;
        int sel = e >> 20;
        int loc = e & 1048575;
        const float* src = sel==0 ? qx : sel==1 ? kx : vx;
        short* dst = xb + (size_t)sel*OUT_ELEMS;
        float4 v = *(const float4*)&src[(size_t)loc*4];
        bf16x4 o = { f2bf(v.x), f2bf(v.y), f2bf(v.z), f2bf(v.w) };
        *(bf16x4*)&dst[(size_t)loc*4] = o;
    } else {                                     // 65536 table entries
        int e = i - 4194304;
        int j = e & 31, s = e >> 5;
        float ang = (float)s * exp2f(-(float)j * 0.41524101186092437f);
        float sn, cs; sincosf(ang, &sn, &cs);    // accurate large-arg reduction
        tab[(size_t)s*64 + j*2]     = cs;
        tab[(size_t)s*64 + j*2 + 1] = sn;
    }
}

// ---------------------------------------------------------------------------
// Fused QKV projection, pure bf16, BK=64, source-pre-swizzled staging
// (conflict-free fragment reads).  z=0: Q (rope fused) -> qb.
// z=1: K (rope fused) -> kb.  z=2: V -> vbt TRANSPOSED [bh][d][s].
// ---------------------------------------------------------------------------
__global__ __launch_bounds__(256) void gemm_qkv(const short* __restrict__ xb,
                                                const short* __restrict__ wqkv,
                                                const float* __restrict__ tab,
                                                short* __restrict__ qb,
                                                short* __restrict__ kb,
                                                short* __restrict__ vbt)
{
    const int z = blockIdx.z;
    const short* A = xb + (size_t)z*OUT_ELEMS;
    const short* B = wqkv + (size_t)z*D_MODEL*D_MODEL;

    __shared__ __align__(16) short Alds[128*64];   // 16 KB, rows of 64 bf16
    __shared__ __align__(16) short Blds[128*64];
    const int t = threadIdx.x, lane = t & 63, wid = t >> 6;
    const int m0 = blockIdx.y << 7, n0 = blockIdx.x << 7;
    const int wm = (wid >> 1) << 6, wn = (wid & 1) << 6;
    const int l15 = lane & 15, l4 = lane >> 4;
    const int gchunk = (lane & 7) ^ (lane >> 3);   // pre-swizzled k-chunk
    const int rxor = l15 & 7;                      // read-side XOR (row&7)

    f32x4 acc[4][4] = {};

    for (int k0 = 0; k0 < D_MODEL; k0 += 64) {
        __syncthreads();
        #pragma unroll
        for (int u = 0; u < 4; ++u) {
            int row = u*32 + wid*8 + (lane >> 3);  // = (u*256+t)>>3
            const short* ga = &A[(size_t)(m0 + row)*D_MODEL + k0 + gchunk*8];
            const short* gb = &B[(size_t)(n0 + row)*D_MODEL + k0 + gchunk*8];
            __builtin_amdgcn_global_load_lds((const AS1 unsigned*)ga,
                (AS3 unsigned*)&Alds[u*2048 + wid*512], 16, 0, 0);
            __builtin_amdgcn_global_load_lds((const AS1 unsigned*)gb,
                (AS3 unsigned*)&Blds[u*2048 + wid*512], 16, 0, 0);
        }
        __syncthreads();
        #pragma unroll
        for (int kk = 0; kk < 2; ++kk) {
            bf16x8 af[4], bfr[4];
            #pragma unroll
            for (int mf = 0; mf < 4; ++mf)
                af[mf] = *(const bf16x8*)&Alds[(wm + mf*16 + l15)*64
                                               + ((kk*4 + l4) ^ rxor)*8];
            #pragma unroll
            for (int nf = 0; nf < 4; ++nf)
                bfr[nf] = *(const bf16x8*)&Blds[(wn + nf*16 + l15)*64
                                                + ((kk*4 + l4) ^ rxor)*8];
            #pragma unroll
            for (int mf = 0; mf < 4; ++mf)
                #pragma unroll
                for (int nf = 0; nf < 4; ++nf)
                    acc[mf][nf] = MFMA16(af[mf], bfr[nf], acc[mf][nf]);
        }
    }

    // C/D layout: col = lane&15, row = (lane>>4)*4 + j
    if (z < 2) {
        short* C = z==0 ? qb : kb;
        #pragma unroll
        for (int mf = 0; mf < 4; ++mf)
            #pragma unroll
            for (int j = 0; j < 4; ++j) {
                int row = m0 + wm + mf*16 + l4*4 + j;
                int s = row & (SEQ-1);
                #pragma unroll
                for (int p = 0; p < 2; ++p) {          // (d, d+32) pairs
                    int d31 = p*16 + l15;              // rotation index 0..31
                    float2 cs2 = *(const float2*)&tab[(size_t)s*64 + d31*2];
                    float x1 = acc[mf][p][j], x2 = acc[mf][p+2][j];
                    size_t rb = (size_t)row*D_MODEL + n0 + wn;
                    C[rb + p*16 + l15]       = f2bf(x1*cs2.x - x2*cs2.y);
                    C[rb + (p+2)*16 + l15]   = f2bf(x1*cs2.y + x2*cs2.x);
                }
            }
    } else {
        #pragma unroll
        for (int nf = 0; nf < 4; ++nf) {
            int col = n0 + wn + nf*16 + l15;
            int hh = col >> 6, d = col & 63;
            #pragma unroll
            for (int mf = 0; mf < 4; ++mf)
                #pragma unroll
                for (int j = 0; j < 4; ++j) {
                    int row = m0 + wm + mf*16 + l4*4 + j;
                    int b = row >> 11, s = row & (SEQ-1);
                    vbt[(((size_t)(b*NH + hh))*DH + d)*SEQ + s] = f2bf(acc[mf][nf][j]);
                }
        }
    }
}

// ---------------------------------------------------------------------------
// Output projection, same BK=64 swizzled structure: out = aob@wob^T + bo.
// ---------------------------------------------------------------------------
__global__ __launch_bounds__(256) void gemm_out(const short* __restrict__ A,
                                                const short* __restrict__ B,
                                                const float* __restrict__ bias,
                                                float* __restrict__ Cout)
{
    __shared__ __align__(16) short Alds[128*64];
    __shared__ __align__(16) short Blds[128*64];
    const int t = threadIdx.x, lane = t & 63, wid = t >> 6;
    const int m0 = blockIdx.y << 7, n0 = blockIdx.x << 7;
    const int wm = (wid >> 1) << 6, wn = (wid & 1) << 6;
    const int l15 = lane & 15, l4 = lane >> 4;
    const int gchunk = (lane & 7) ^ (lane >> 3);
    const int rxor = l15 & 7;

    f32x4 acc[4][4] = {};

    for (int k0 = 0; k0 < D_MODEL; k0 += 64) {
        __syncthreads();
        #pragma unroll
        for (int u = 0; u < 4; ++u) {
            int row = u*32 + wid*8 + (lane >> 3);
            const short* ga = &A[(size_t)(m0 + row)*D_MODEL + k0 + gchunk*8];
            const short* gb = &B[(size_t)(n0 + row)*D_MODEL + k0 + gchunk*8];
            __builtin_amdgcn_global_load_lds((const AS1 unsigned*)ga,
                (AS3 unsigned*)&Alds[u*2048 + wid*512], 16, 0, 0);
            __builtin_amdgcn_global_load_lds((const AS1 unsigned*)gb,
                (AS3 unsigned*)&Blds[u*2048 + wid*512], 16, 0, 0);
        }
        __syncthreads();
        #pragma unroll
        for (int kk = 0; kk < 2; ++kk) {
            bf16x8 af[4], bfr[4];
            #pragma unroll
            for (int mf = 0; mf < 4; ++mf)
                af[mf] = *(const bf16x8*)&Alds[(wm + mf*16 + l15)*64
                                               + ((kk*4 + l4) ^ rxor)*8];
            #pragma unroll
            for (int nf = 0; nf < 4; ++nf)
                bfr[nf] = *(const bf16x8*)&Blds[(wn + nf*16 + l15)*64
                                                + ((kk*4 + l4) ^ rxor)*8];
            #pragma unroll
            for (int mf = 0; mf < 4; ++mf)
                #pragma unroll
                for (int nf = 0; nf < 4; ++nf)
                    acc[mf][nf] = MFMA16(af[mf], bfr[nf], acc[mf][nf]);
        }
    }

    #pragma unroll
    for (int nf = 0; nf < 4; ++nf) {
        int col = n0 + wn + nf*16 + l15;
        float bv = bias[col];
        #pragma unroll
        for (int mf = 0; mf < 4; ++mf)
            #pragma unroll
            for (int j = 0; j < 4; ++j) {
                int row = m0 + wm + mf*16 + l4*4 + j;
                Cout[(size_t)row*D_MODEL + col] = acc[mf][nf][j] + bv;
            }
    }
}

// ---------------------------------------------------------------------------
// Fused two-loop flash attention (r14-best structure: 8 waves x 16 q-rows,
// __syncthreads, dbuf K/V staging, swapped QK^T -> P[k][q] q=lane&15,
// fixed-max softmax, NT f32x4 weight stores, b64 P-pack wave-private).
// NEW: weights via exp2(fma(s, c, -log2 lsum)) (mul folded into exponent)
// and HW cvt_pk bf16 conversion for the P-pack.
// Block = (b,h,128 q-rows), 512 thr, LDS 48 KB -> 3 blocks/CU.
// ---------------------------------------------------------------------------
__global__ __launch_bounds__(512) void attn_fused(const short* __restrict__ qb,
                                                  const short* __restrict__ kb,
                                                  const short* __restrict__ vbt,
                                                  float* __restrict__ attn,
                                                  short* __restrict__ aob)
{
    __shared__ __align__(16) short Klds[2][64*64];
    __shared__ __align__(16) short Vt  [2][64*64];
    __shared__ __align__(16) short Plds[8*16*64];
    const int t = threadIdx.x, lane = t & 63, wv = t >> 6;
    const int bid = blockIdx.x;
    const int nb = (bid & 7)*64 + (bid >> 3);       // XCD swizzle (512 = 8*64)
    const int rb = nb & 15, bh = nb >> 4;           // bh = b*16+h
    const int h = bh & 15;
    const size_t bs0 = (size_t)(bh >> 4) * SEQ;
    const int qrow0 = rb << 7;
    const int l15 = lane & 15, l4 = lane >> 4;
    const int srow = t >> 3, ssl = t & 7;           // staging row/slot
    const int soff = srow*64 + swz8(srow, ssl)*8;   // staging LDS offset

    // Q fragments (B-operand: lane&15 = q-column of the score tile)
    bf16x8 qf[2];
    {
        int qrow = qrow0 + wv*16 + l15;
        const short* qp = &qb[(bs0 + qrow)*D_MODEL + h*DH + l4*8];
        qf[0] = *(const bf16x8*)&qp[0];
        qf[1] = *(const bf16x8*)&qp[32];
    }

    const short* kbase  = &kb[(bs0 + srow)*D_MODEL + h*DH + ssl*8];
    const short* vtbase = &vbt[((size_t)bh*DH + srow)*SEQ + ssl*8];

    // ---- loop 1: denominator (fixed max = 0, lane-local partial sums) ---
    float lsum = 0.f;
    {
        bf16x8 kreg = *(const bf16x8*)&kbase[0];
        *(bf16x8*)&Klds[0][soff] = kreg;
        kreg = *(const bf16x8*)&kbase[(size_t)64*D_MODEL];
        __syncthreads();
        int cur = 0;
        for (int kt = 0; kt < SEQ; kt += 64, cur ^= 1) {
            if (kt + 64 < SEQ) {
                *(bf16x8*)&Klds[cur^1][soff] = kreg;
                if (kt + 128 < SEQ)
                    kreg = *(const bf16x8*)&kbase[(size_t)(kt+128)*D_MODEL];
            }
            f32x4 sc[4] = {};
            __builtin_amdgcn_s_setprio(1);
            #pragma unroll
            for (int kk = 0; kk < 2; ++kk)
                #pragma unroll
                for (int nf = 0; nf < 4; ++nf) {
                    int krow = nf*16 + l15;
                    bf16x8 kf = *(const bf16x8*)&Klds[cur][krow*64 + swz8(krow, kk*4 + l4)*8];
                    sc[nf] = MFMA16(kf, qf[kk], sc[nf]);   // swapped: D[k][q]
                }
            __builtin_amdgcn_s_setprio(0);
            #pragma unroll
            for (int nf = 0; nf < 4; ++nf)
                #pragma unroll
                for (int j = 0; j < 4; ++j)
                    lsum += exp2f(sc[nf][j]*EXPSC);
            __syncthreads();
        }
    }
    lsum += __shfl_xor(lsum, 16);
    lsum += __shfl_xor(lsum, 32);
    const float mL = -log2f(lsum);       // fold 1/lsum into the exponent

    // ---- loop 2: weights + PV -------------------------------------------
    f32x4 o[4] = {};
    const size_t wrow = ((size_t)bh*SEQ + qrow0 + wv*16 + l15)*SEQ;
    short* pbase = &Plds[wv*1024 + l15*64];
    {
        bf16x8 kreg = *(const bf16x8*)&kbase[0];
        bf16x8 vreg = *(const bf16x8*)&vtbase[0];
        *(bf16x8*)&Klds[0][soff] = kreg;
        *(bf16x8*)&Vt  [0][soff] = vreg;             // srow = d
        kreg = *(const bf16x8*)&kbase[(size_t)64*D_MODEL];
        vreg = *(const bf16x8*)&vtbase[64];
        __syncthreads();
        int cur = 0;
        for (int kt = 0; kt < SEQ; kt += 64, cur ^= 1) {
            if (kt + 64 < SEQ) {
                *(bf16x8*)&Klds[cur^1][soff] = kreg;
                *(bf16x8*)&Vt  [cur^1][soff] = vreg;
                if (kt + 128 < SEQ) {
                    kreg = *(const bf16x8*)&kbase[(size_t)(kt+128)*D_MODEL];
                    vreg = *(const bf16x8*)&vtbase[kt+128];
                }
            }
            f32x4 sc[4] = {};
            __builtin_amdgcn_s_setprio(1);
            #pragma unroll
            for (int kk = 0; kk < 2; ++kk)
                #pragma unroll
                for (int nf = 0; nf < 4; ++nf) {
                    int krow = nf*16 + l15;
                    bf16x8 kf = *(const bf16x8*)&Klds[cur][krow*64 + swz8(krow, kk*4 + l4)*8];
                    sc[nf] = MFMA16(kf, qf[kk], sc[nf]);
                }
            __builtin_amdgcn_s_setprio(0);
            // lane holds P[k = nf*16 + l4*4 + j][q = l15]
            #pragma unroll
            for (int nf = 0; nf < 4; ++nf) {
                float w0 = exp2f(fmaf(sc[nf][0], EXPSC, mL));
                float w1 = exp2f(fmaf(sc[nf][1], EXPSC, mL));
                float w2 = exp2f(fmaf(sc[nf][2], EXPSC, mL));
                float w3 = exp2f(fmaf(sc[nf][3], EXPSC, mL));
                f32x4 wv4 = { w0, w1, w2, w3 };
                __builtin_nontemporal_store(wv4,
                    (f32x4*)&attn[wrow + kt + nf*16 + l4*4]);
                bf16x4 pw = { f2bf(w0), f2bf(w1), f2bf(w2), f2bf(w3) };
                *(bf16x4*)&pbase[swz8(l15, nf*2 + (l4>>1))*8 + (l4&1)*4] = pw;
            }
            // PV: A = P (wave-private, no barrier), B = Vt staged
            __builtin_amdgcn_s_setprio(1);
            #pragma unroll
            for (int kk = 0; kk < 2; ++kk) {
                bf16x8 pa = *(const bf16x8*)&pbase[swz8(l15, kk*4 + l4)*8];
                #pragma unroll
                for (int nf = 0; nf < 4; ++nf) {
                    int d = nf*16 + l15;
                    bf16x8 vf = *(const bf16x8*)&Vt[cur][d*64 + swz8(d, kk*4 + l4)*8];
                    o[nf] = MFMA16(pa, vf, o[nf]);
                }
            }
            __builtin_amdgcn_s_setprio(0);
            __syncthreads();
        }
    }
    #pragma unroll
    for (int nf = 0; nf < 4; ++nf)
        #pragma unroll
        for (int j = 0; j < 4; ++j) {
            int qr = qrow0 + wv*16 + l4*4 + j;
            aob[(bs0 + qr)*D_MODEL + h*DH + nf*16 + l15] = f2bf(o[nf][j]);
        }
}

// ---------------------------------------------------------------------------
extern "C" void kernel_launch(void* const* d_in, const int* in_sizes, int n_in,
                              void* d_out, int out_size, void* d_ws, size_t ws_size,
                              hipStream_t stream)
{
    const float* query = (const float*)d_in[0];
    const float* key_  = (const float*)d_in[1];
    const float* value = (const float*)d_in[2];
    const float* Wq    = (const float*)d_in[3];
    const float* Wk    = (const float*)d_in[4];
    const float* Wv    = (const float*)d_in[5];
    const float* Wo    = (const float*)d_in[6];
    const float* bo    = (const float*)d_in[7];

    float* out  = (float*)d_out;
    float* attn = out + OUT_ELEMS;
    short* xb   = (short*)attn;                  // 24 MB scratch inside attn
                                                 // slice; overwritten by
                                                 // attn_fused later (safe:
                                                 // stream-ordered)

    // ws (shorts): wqkv 3M | wob 1M | qb 4M | kb 4M | vbt 4M | aob 4M | tab
    short* wqkv = (short*)d_ws;
    short* wob  = wqkv + (size_t)3*1048576;
    short* qb   = wob  + (size_t)1048576;
    short* kb   = qb + OUT_ELEMS;
    short* vbt  = kb + OUT_ELEMS;                // [bh=32][d=64][s=2048]
    short* aob  = vbt + OUT_ELEMS;
    float* tab  = (float*)(aob + OUT_ELEMS);     // 2048*64 floats (512 KB)

    dim3 blk(256);

    hipLaunchKernelGGL(prep, dim3(16640), blk, 0, stream,
                       Wq, Wk, Wv, Wo, query, key_, value, wqkv, wob, xb, tab);
    hipLaunchKernelGGL(gemm_qkv, dim3(8, 32, 3), blk, 0, stream,
                       xb, wqkv, tab, qb, kb, vbt);
    hipLaunchKernelGGL(attn_fused, dim3(512), dim3(512), 0, stream,
                       qb, kb, vbt, attn, aob);
    hipLaunchKernelGGL(gemm_out, dim3(8, 32), blk, 0, stream, aob, wob, bo, out);
}